// Round 5
// baseline (1704.527 us; speedup 1.0000x reference)
//
#include <hip/hip_runtime.h>
#include <math.h>

#define NN 50000
#define EE 800000
#define HH 64
#define RR 8
#define LL 3
#define NR (NN * RR)            // 400000 segments
#define NB ((NR + 255) / 256)   // 1563 scan blocks
#define LN_EPS 1e-5f
#define NEG_SLOPE 0.2f
#define LDH 68                  // LDS row stride (floats) for 16x64 tiles
#define PND 516                 // ps node stride (words): 8*64+4, <=2-way bank aliasing
#define PSW (16 * PND)          // ps words (8256)
#define OTB (16 * LDH)          // o-tile base inside ps (1088)

typedef __attribute__((ext_vector_type(8))) short bf8;
typedef __attribute__((ext_vector_type(4))) float f4;
typedef __attribute__((ext_vector_type(8))) unsigned short us8;
typedef __attribute__((ext_vector_type(2))) unsigned int u2;

__device__ __forceinline__ unsigned short bf16r(float f) {
    unsigned u = __float_as_uint(f);
    unsigned r = u + 0x7fffu + ((u >> 16) & 1u);
    return (unsigned short)(r >> 16);
}
__device__ __forceinline__ float bf2f(unsigned short u) {
    return __uint_as_float(((unsigned)u) << 16);
}

// out[n,k] = (relu?) dot(in[n,:], W[k,:]) + bias[k]   (64x64 weight)
template<bool RELU>
__global__ void proj64(const float* __restrict__ in, const float* __restrict__ W,
                       const float* __restrict__ bias, float* __restrict__ out) {
    __shared__ float WT[64 * 65];
    __shared__ float xs[4 * 64];
    int tid = threadIdx.x;
    #pragma unroll
    for (int s = 0; s < 16; ++s) {
        int idx = tid + 256 * s;
        int k = idx >> 6, i = idx & 63;
        WT[i * 65 + k] = W[idx];
    }
    int w = tid >> 6, l = tid & 63;
    int n = blockIdx.x * 4 + w;
    if (n < NN) xs[w * 64 + l] = in[n * 64 + l];
    __syncthreads();
    if (n >= NN) return;
    float acc = 0.f;
    #pragma unroll
    for (int i = 0; i < 64; ++i) acc += xs[w * 64 + i] * WT[i * 65 + l];
    acc += bias[l];
    if (RELU) acc = fmaxf(acc, 0.f);
    out[n * 64 + l] = acc;
}

// layer-0 only: s_src[n,r], s_dst[n,r] from h; emit bf16 mirror
__global__ void att_pre(const float* __restrict__ h, const float* __restrict__ W_att,
                        float* __restrict__ s_src, float* __restrict__ s_dst,
                        unsigned short* __restrict__ hbf) {
    __shared__ float hs[32 * 65];
    __shared__ float was[8 * 65];
    __shared__ float wad[8 * 65];
    int tid = threadIdx.x;
    int n0 = blockIdx.x * 32;
    #pragma unroll
    for (int s = 0; s < 4; ++s) {
        int idx = tid + 256 * s;
        int r = idx >> 7, c = idx & 127;
        float v = W_att[idx];
        if (c < 64) was[r * 65 + c] = v;
        else        wad[r * 65 + (c - 64)] = v;
    }
    #pragma unroll
    for (int s = 0; s < 8; ++s) {
        int idx = tid + 256 * s;
        int nl = idx >> 6, c = idx & 63;
        int n = n0 + nl;
        float v = 0.f;
        if (n < NN) {
            v = h[(size_t)n * 64 + c];
            hbf[(size_t)n * 64 + c] = bf16r(v);
        }
        hs[nl * 65 + c] = v;
    }
    __syncthreads();
    int nl = tid >> 3, r = tid & 7;
    int n = n0 + nl;
    if (n >= NN) return;
    float as = 0.f, ad = 0.f;
    #pragma unroll
    for (int k = 0; k < 64; ++k) {
        float hv = hs[nl * 65 + k];
        as += hv * was[r * 65 + k];
        ad += hv * wad[r * 65 + k];
    }
    s_src[n * 8 + r] = as;
    s_dst[n * 8 + r] = ad;
}

// ---- one-time CSR build (compact, exact) ----
__global__ void edge_count(const int* __restrict__ ei, const int* __restrict__ et,
                           int* __restrict__ counts, int* __restrict__ rank) {
    int e = blockIdx.x * 256 + threadIdx.x;
    int d = ei[EE + e], t = et[e];
    rank[e] = atomicAdd(&counts[d * 8 + t], 1);
}

__global__ void scan1(const int* __restrict__ counts, int* __restrict__ offs,
                      int* __restrict__ bsum) {
    __shared__ int s[256];
    int tid = threadIdx.x;
    int i = blockIdx.x * 256 + tid;
    int v = (i < NR) ? counts[i] : 0;
    s[tid] = v; __syncthreads();
    for (int d = 1; d < 256; d <<= 1) {
        int x = (tid >= d) ? s[tid - d] : 0;
        __syncthreads();
        s[tid] += x;
        __syncthreads();
    }
    if (i < NR) offs[i] = s[tid] - v;
    if (tid == 255) bsum[blockIdx.x] = s[255];
}

__global__ void scan2(int* __restrict__ bsum) {
    __shared__ int s[256];
    int tid = threadIdx.x;
    int carry = 0;
    for (int c0 = 0; c0 < NB; c0 += 256) {
        int i = c0 + tid;
        int v = (i < NB) ? bsum[i] : 0;
        s[tid] = v; __syncthreads();
        for (int d = 1; d < 256; d <<= 1) {
            int x = (tid >= d) ? s[tid - d] : 0;
            __syncthreads();
            s[tid] += x;
            __syncthreads();
        }
        if (i < NB) bsum[i] = carry + s[tid] - v;
        int tot = s[255];
        __syncthreads();
        carry += tot;
    }
}

__global__ void scan3(int* __restrict__ offs, const int* __restrict__ bsum) {
    int i = blockIdx.x * 256 + threadIdx.x;
    if (i < NR) offs[i] += bsum[i >> 8];
}

__global__ void edge_fill(const int* __restrict__ ei, const int* __restrict__ et,
                          const int* __restrict__ rank, const int* __restrict__ offs,
                          int* __restrict__ esrc_c, int* __restrict__ eseg_c) {
    int e = blockIdx.x * 256 + threadIdx.x;
    int s = ei[e], d = ei[EE + e], t = et[e];
    int seg = d * 8 + t;
    int slot = offs[seg] + rank[e];
    esrc_c[slot] = s;
    eseg_c[slot] = seg;
}

// weights -> bf16: WrB/WgB [r][kout][kd]; WaB [16][64] (rows 0-7 = Wa_src r, 8-15 = Wa_dst r)
__global__ void cvt_w(const float* __restrict__ Wr, const float* __restrict__ Wg,
                      const float* __restrict__ Wa,
                      unsigned short* __restrict__ WrB, unsigned short* __restrict__ WgB,
                      unsigned short* __restrict__ WaB) {
    int i = blockIdx.x * 256 + threadIdx.x;   // 32768 total
    WrB[i] = bf16r(Wr[i]);
    WgB[i] = bf16r(Wg[i]);
    if (i < 1024) {
        int row = i >> 6, k = i & 63;
        float v = (row < 8) ? Wa[row * 128 + k] : Wa[(row - 8) * 128 + 64 + k];
        WaB[i] = bf16r(v);
    }
}

// slot-parallel softmax: ex_c[slot] = exp(leaky(s_src+s_dst+b)); per-type denom
// (no max subtraction: |score|<~8, fp32-safe; softmax ratio shift-invariant)
__global__ void edge_softmax2(const int* __restrict__ esrc_c, const int* __restrict__ eseg_c,
                              const float* __restrict__ s_src, const float* __restrict__ s_dst,
                              const float* __restrict__ b_att,
                              float* __restrict__ ex_c, float* __restrict__ denomL) {
    __shared__ float lsum[4][8];
    int tid = threadIdx.x;
    if (tid < 32) lsum[tid >> 3][tid & 7] = 0.f;
    __syncthreads();
    int slot = blockIdx.x * 256 + tid;     // EE % 256 == 0
    int src = esrc_c[slot];
    int seg = eseg_c[slot];
    int t = seg & 7;
    float sc = s_src[src * 8 + t] + s_dst[seg] + b_att[t];
    sc = (sc >= 0.f) ? sc : NEG_SLOPE * sc;
    float ex = __expf(sc);
    ex_c[slot] = ex;
    atomicAdd(&lsum[tid >> 6][t], ex);
    __syncthreads();
    if (tid < 32) atomicAdd(&denomL[tid & 7], lsum[tid >> 3][tid & 7]);
}

// Fused combine, 16-node tiles, edge-flat gather with LDS atomics.
// EMIT: also compute next-layer s_src/s_dst (MFMA vs WaB) + bf16 mirror.
template<bool EMIT>
__global__ __launch_bounds__(256, 4) void combine_fused(
    const float* __restrict__ hbuf, const unsigned short* __restrict__ hbf_in,
    const int* __restrict__ offs, const int* __restrict__ esrc_c,
    const int* __restrict__ eseg_c, const float* __restrict__ ex_c,
    const float* __restrict__ denomL,
    const unsigned short* __restrict__ WrB, const unsigned short* __restrict__ WgB,
    const unsigned short* __restrict__ WaB, const float* __restrict__ b_gate,
    const float* __restrict__ gamma, const float* __restrict__ beta,
    float* __restrict__ hout, unsigned short* __restrict__ hbf_out,
    float* __restrict__ ssrc_out, float* __restrict__ sdst_out) {
    __shared__ float hs[16 * LDH];
    __shared__ float ps[PSW];
    __shared__ float idn[8];
    int tid = threadIdx.x;
    int n0 = blockIdx.x * 16;

    // stage h tile (fp32), one float4 per thread
    {
        int row = tid >> 4, c4 = tid & 15;
        int n = n0 + row;
        f4 v = {0.f, 0.f, 0.f, 0.f};
        if (n < NN) v = ((const f4*)hbuf)[(size_t)n * 16 + c4];
        *(f4*)&hs[row * LDH + c4 * 4] = v;
    }
    // zero ps
    for (int i = tid; i < PSW / 4; i += 256)
        ((f4*)ps)[i] = (f4){0.f, 0.f, 0.f, 0.f};
    if (tid < 8) idn[tid] = 1.f / denomL[tid];
    __syncthreads();

    int w = tid >> 6, lane = tid & 63;
    int quad = lane >> 4, lr = lane & 15;

    // A_h fragments
    bf8 a_h[2];
    #pragma unroll
    for (int kb = 0; kb < 2; ++kb) {
        const float* p = &hs[lr * LDH + kb * 32 + quad * 8];
        bf8 a;
        #pragma unroll
        for (int j = 0; j < 8; ++j) a[j] = (short)bf16r(p[j]);
        a_h[kb] = a;
    }

    // ---- edge-flat gather: items = edges x 8 chunks ----
    {
        int segLo = n0 * 8;
        int segHi = (n0 + 16 < NN ? n0 + 16 : NN) * 8;
        int base = offs[segLo];
        int eEnd = (segHi >= NR) ? EE : offs[segHi];
        int nIt = (eEnd - base) * 8;
        for (int it = tid; it < nIt; it += 256) {
            int slot = base + (it >> 3);
            int ch = it & 7;
            int src = esrc_c[slot];
            int seg = eseg_c[slot];
            float att = ex_c[slot] * idn[seg & 7];
            us8 hv = *(const us8*)(hbf_in + ((size_t)src << 6) + ch * 8);
            int pbase = ((seg >> 3) - n0) * PND + (seg & 7) * 64 + ch * 8;
            #pragma unroll
            for (int j = 0; j < 8; ++j)
                atomicAdd(&ps[pbase + j], att * bf2f(hv[j]));
        }
    }
    __syncthreads();

    // ---- 8 relation MFMA phases (no barriers inside) ----
    f4 acc = (f4){0.f, 0.f, 0.f, 0.f};
    int tn = w;                       // this wave's 16 output cols
    for (int r = 0; r < 8; ++r) {
        bf8 a_p[2];
        #pragma unroll
        for (int kb = 0; kb < 2; ++kb) {
            const float* p = &ps[lr * PND + r * 64 + kb * 32 + quad * 8];
            bf8 a;
            #pragma unroll
            for (int j = 0; j < 8; ++j) a[j] = (short)bf16r(p[j]);
            a_p[kb] = a;
        }
        f4 aggc = (f4){0.f, 0.f, 0.f, 0.f};
        f4 gacc = (f4){0.f, 0.f, 0.f, 0.f};
        #pragma unroll
        for (int kb = 0; kb < 2; ++kb) {
            const bf8* br = (const bf8*)(WrB + ((r * 64 + tn * 16 + lr) * 64 + kb * 32 + quad * 8));
            const bf8* bg = (const bf8*)(WgB + ((r * 64 + tn * 16 + lr) * 64 + kb * 32 + quad * 8));
            aggc = __builtin_amdgcn_mfma_f32_16x16x32_bf16(a_p[kb], *br, aggc, 0, 0, 0);
            gacc = __builtin_amdgcn_mfma_f32_16x16x32_bf16(a_h[kb], *bg, gacc, 0, 0, 0);
        }
        float bg = b_gate[r * 64 + tn * 16 + lr];
        #pragma unroll
        for (int j = 0; j < 4; ++j) {
            float g = 1.f / (1.f + __expf(-(gacc[j] + bg)));
            acc[j] += g * aggc[j];
        }
    }
    __syncthreads();   // ps fully consumed by all waves before reuse

    // t = h + acc/8 into ps[0..OTB) (stride LDH), C-layout positions
    #pragma unroll
    for (int j = 0; j < 4; ++j) {
        int row = quad * 4 + j;
        int col = tn * 16 + lr;
        ps[row * LDH + col] = hs[row * LDH + col] + acc[j] * 0.125f;
    }
    __syncthreads();

    // LN + ReLU; store hout; EMIT: o-tile + bf16 mirror
    {
        int row = tid >> 4, c = tid & 15;
        int n = n0 + row;
        f4 tv = *(const f4*)&ps[row * LDH + c * 4];
        float s1 = tv[0] + tv[1] + tv[2] + tv[3];
        float s2 = tv[0]*tv[0] + tv[1]*tv[1] + tv[2]*tv[2] + tv[3]*tv[3];
        #pragma unroll
        for (int off = 1; off <= 8; off <<= 1) {
            s1 += __shfl_xor(s1, off, 64);
            s2 += __shfl_xor(s2, off, 64);
        }
        float mu = s1 * (1.f / 64.f);
        float var = s2 * (1.f / 64.f) - mu * mu;
        float rs = rsqrtf(var + LN_EPS);
        f4 g = *(const f4*)(gamma + c * 4);
        f4 b = *(const f4*)(beta + c * 4);
        f4 ov;
        #pragma unroll
        for (int j = 0; j < 4; ++j)
            ov[j] = fmaxf((tv[j] - mu) * rs * g[j] + b[j], 0.f);
        if (n < NN)
            *(f4*)(hout + (size_t)n * 64 + c * 4) = ov;
        if (EMIT) {
            *(f4*)&ps[OTB + row * LDH + c * 4] = ov;
            if (n < NN) {
                u2 u;
                u[0] = (unsigned)bf16r(ov[0]) | ((unsigned)bf16r(ov[1]) << 16);
                u[1] = (unsigned)bf16r(ov[2]) | ((unsigned)bf16r(ov[3]) << 16);
                *(u2*)(hbf_out + (size_t)n * 64 + c * 4) = u;
            }
        }
    }

    if (EMIT) {
        __syncthreads();
        if (w == 0) {
            f4 sc = (f4){0.f, 0.f, 0.f, 0.f};
            #pragma unroll
            for (int kb = 0; kb < 2; ++kb) {
                const float* p = &ps[OTB + lr * LDH + kb * 32 + quad * 8];
                bf8 a;
                #pragma unroll
                for (int j = 0; j < 8; ++j) a[j] = (short)bf16r(p[j]);
                const bf8* bw = (const bf8*)(WaB + lr * 64 + kb * 32 + quad * 8);
                sc = __builtin_amdgcn_mfma_f32_16x16x32_bf16(a, *bw, sc, 0, 0, 0);
            }
            #pragma unroll
            for (int j = 0; j < 4; ++j) {
                int n = n0 + quad * 4 + j;
                if (n < NN) {
                    if (lr < 8) ssrc_out[n * 8 + lr] = sc[j];
                    else        sdst_out[n * 8 + (lr - 8)] = sc[j];
                }
            }
        }
    }
}

extern "C" void kernel_launch(void* const* d_in, const int* in_sizes, int n_in,
                              void* d_out, int out_size, void* d_ws, size_t ws_size,
                              hipStream_t stream) {
    const float* x      = (const float*)d_in[0];
    const int*   ei     = (const int*)d_in[1];
    const int*   et     = (const int*)d_in[2];
    const float* W_in   = (const float*)d_in[3];
    const float* b_in   = (const float*)d_in[4];
    const float* W_rel  = (const float*)d_in[5];
    const float* W_gate = (const float*)d_in[6];
    const float* b_gate = (const float*)d_in[7];
    const float* W_att  = (const float*)d_in[8];
    const float* b_att  = (const float*)d_in[9];
    const float* ln_g   = (const float*)d_in[10];
    const float* ln_b   = (const float*)d_in[11];
    const float* W_out  = (const float*)d_in[12];
    const float* b_out  = (const float*)d_in[13];
    float* out = (float*)d_out;

    float* h0 = (float*)d_out;          // ping-pong A (scratch until final proj)

    char* ws = (char*)d_ws;
    float* h1 = (float*)ws;                     ws += (size_t)NN * 64 * 4;
    unsigned short* hbfA = (unsigned short*)ws; ws += (size_t)NN * 64 * 2;
    unsigned short* hbfB = (unsigned short*)ws; ws += (size_t)NN * 64 * 2;
    float* s_src = (float*)ws;                  ws += (size_t)NN * 8 * 4;
    float* s_dst = (float*)ws;                  ws += (size_t)NN * 8 * 4;
    unsigned short* WrB = (unsigned short*)ws;  ws += (size_t)RR * 64 * 64 * 2;
    unsigned short* WgB = (unsigned short*)ws;  ws += (size_t)RR * 64 * 64 * 2;
    unsigned short* WaB = (unsigned short*)ws;  ws += 2048;
    int* counts = (int*)ws;                     ws += (size_t)NR * 4;
    float* denoms = (float*)ws;                 ws += 128;       // 3x8 + pad
    int* offs = (int*)ws;                       ws += (size_t)NR * 4;
    int* bsum = (int*)ws;                       ws += 6400;
    int* rank = (int*)ws;                       ws += (size_t)EE * 4;
    int* esrc_c = (int*)ws;                     ws += (size_t)EE * 4;
    int* eseg_c = (int*)ws;                     ws += (size_t)EE * 4;
    float* ex_c = (float*)ws;                   ws += (size_t)EE * 4;

    hipMemsetAsync(counts, 0, (size_t)NR * 4 + 128, stream);    // counts + denoms
    cvt_w<<<128, 256, 0, stream>>>(W_rel, W_gate, W_att, WrB, WgB, WaB);
    edge_count<<<EE / 256, 256, 0, stream>>>(ei, et, counts, rank);
    scan1<<<NB, 256, 0, stream>>>(counts, offs, bsum);
    scan2<<<1, 256, 0, stream>>>(bsum);
    scan3<<<NB, 256, 0, stream>>>(offs, bsum);
    edge_fill<<<EE / 256, 256, 0, stream>>>(ei, et, rank, offs, esrc_c, eseg_c);
    proj64<true><<<(NN + 3) / 4, 256, 0, stream>>>(x, W_in, b_in, h0);
    att_pre<<<(NN + 31) / 32, 256, 0, stream>>>(h0, W_att, s_src, s_dst, hbfA);

    const int tiles16 = (NN + 15) / 16;   // 3125
    float* hA = h0;  float* hB = h1;
    unsigned short* bfA = hbfA;  unsigned short* bfB = hbfB;
    for (int layer = 0; layer < LL; ++layer) {
        edge_softmax2<<<EE / 256, 256, 0, stream>>>(esrc_c, eseg_c, s_src, s_dst,
                                                    b_att, ex_c, denoms + 8 * layer);
        if (layer < LL - 1) {
            combine_fused<true><<<tiles16, 256, 0, stream>>>(
                hA, bfA, offs, esrc_c, eseg_c, ex_c, denoms + 8 * layer,
                WrB, WgB, WaB, b_gate, ln_g + layer * 64, ln_b + layer * 64,
                hB, bfB, s_src, s_dst);
        } else {
            combine_fused<false><<<tiles16, 256, 0, stream>>>(
                hA, bfA, offs, esrc_c, eseg_c, ex_c, denoms + 8 * layer,
                WrB, WgB, WaB, b_gate, ln_g + layer * 64, ln_b + layer * 64,
                hB, bfB, s_src, s_dst);
        }
        float* tf = hA; hA = hB; hB = tf;
        unsigned short* tb = bfA; bfA = bfB; bfB = tb;
    }
    proj64<false><<<(NN + 3) / 4, 256, 0, stream>>>(hA, W_out, b_out, out);
}

// Round 6
// 1184.872 us; speedup vs baseline: 1.4386x; 1.4386x over previous
//
#include <hip/hip_runtime.h>
#include <math.h>

#define NN 50000
#define EE 800000
#define HH 64
#define RR 8
#define LL 3
#define NR (NN * RR)            // 400000 segments
#define NB ((NR + 255) / 256)   // scan blocks
#define LN_EPS 1e-5f
#define NEG_SLOPE 0.2f
#define LDH 68                  // LDS row stride (floats) for 16x64 tiles
#define PND 516                 // ps node stride (words): 8*64+4 -> 2-way bank aliasing max
#define PSW (16 * PND)
#define OTB (16 * LDH)          // o-tile base inside ps (EMIT epilogue)

typedef __attribute__((ext_vector_type(8))) short bf8;
typedef __attribute__((ext_vector_type(4))) float f4;
typedef __attribute__((ext_vector_type(4))) unsigned short us4;
typedef __attribute__((ext_vector_type(2))) unsigned int u2;

__device__ __forceinline__ unsigned short bf16r(float f) {
    unsigned u = __float_as_uint(f);
    unsigned r = u + 0x7fffu + ((u >> 16) & 1u);
    return (unsigned short)(r >> 16);
}
__device__ __forceinline__ float bf2f(unsigned short u) {
    return __uint_as_float(((unsigned)u) << 16);
}

// out[n,k] = (relu?) dot(in[n,:], W[k,:]) + bias[k]   (64x64 weight)
template<bool RELU>
__global__ void proj64(const float* __restrict__ in, const float* __restrict__ W,
                       const float* __restrict__ bias, float* __restrict__ out) {
    __shared__ float WT[64 * 65];
    __shared__ float xs[4 * 64];
    int tid = threadIdx.x;
    #pragma unroll
    for (int s = 0; s < 16; ++s) {
        int idx = tid + 256 * s;
        int k = idx >> 6, i = idx & 63;
        WT[i * 65 + k] = W[idx];
    }
    int w = tid >> 6, l = tid & 63;
    int n = blockIdx.x * 4 + w;
    if (n < NN) xs[w * 64 + l] = in[n * 64 + l];
    __syncthreads();
    if (n >= NN) return;
    float acc = 0.f;
    #pragma unroll
    for (int i = 0; i < 64; ++i) acc += xs[w * 64 + i] * WT[i * 65 + l];
    acc += bias[l];
    if (RELU) acc = fmaxf(acc, 0.f);
    out[n * 64 + l] = acc;
}

// layer-0 only: s_src[n,r], s_dst[n,r] from h; emit bf16 mirror
__global__ void att_pre(const float* __restrict__ h, const float* __restrict__ W_att,
                        float* __restrict__ s_src, float* __restrict__ s_dst,
                        unsigned short* __restrict__ hbf) {
    __shared__ float hs[32 * 65];
    __shared__ float was[8 * 65];
    __shared__ float wad[8 * 65];
    int tid = threadIdx.x;
    int n0 = blockIdx.x * 32;
    #pragma unroll
    for (int s = 0; s < 4; ++s) {
        int idx = tid + 256 * s;
        int r = idx >> 7, c = idx & 127;
        float v = W_att[idx];
        if (c < 64) was[r * 65 + c] = v;
        else        wad[r * 65 + (c - 64)] = v;
    }
    #pragma unroll
    for (int s = 0; s < 8; ++s) {
        int idx = tid + 256 * s;
        int nl = idx >> 6, c = idx & 63;
        int n = n0 + nl;
        float v = 0.f;
        if (n < NN) {
            v = h[(size_t)n * 64 + c];
            hbf[(size_t)n * 64 + c] = bf16r(v);
        }
        hs[nl * 65 + c] = v;
    }
    __syncthreads();
    int nl = tid >> 3, r = tid & 7;
    int n = n0 + nl;
    if (n >= NN) return;
    float as = 0.f, ad = 0.f;
    #pragma unroll
    for (int k = 0; k < 64; ++k) {
        float hv = hs[nl * 65 + k];
        as += hv * was[r * 65 + k];
        ad += hv * wad[r * 65 + k];
    }
    s_src[n * 8 + r] = as;
    s_dst[n * 8 + r] = ad;
}

// ---- one-time CSR build (compact, exact) ----
__global__ void edge_count(const int* __restrict__ ei, const int* __restrict__ et,
                           int* __restrict__ counts, int* __restrict__ rank) {
    int e = blockIdx.x * 256 + threadIdx.x;
    int d = ei[EE + e], t = et[e];
    rank[e] = atomicAdd(&counts[d * 8 + t], 1);
}

__global__ void scan1(const int* __restrict__ counts, int* __restrict__ offs,
                      int* __restrict__ bsum) {
    __shared__ int s[256];
    int tid = threadIdx.x;
    int i = blockIdx.x * 256 + tid;
    int v = (i < NR) ? counts[i] : 0;
    s[tid] = v; __syncthreads();
    for (int d = 1; d < 256; d <<= 1) {
        int x = (tid >= d) ? s[tid - d] : 0;
        __syncthreads();
        s[tid] += x;
        __syncthreads();
    }
    if (i < NR) offs[i] = s[tid] - v;
    if (tid == 255) bsum[blockIdx.x] = s[255];
}

__global__ void scan2(int* __restrict__ bsum) {
    __shared__ int s[256];
    int tid = threadIdx.x;
    int carry = 0;
    for (int c0 = 0; c0 < NB; c0 += 256) {
        int i = c0 + tid;
        int v = (i < NB) ? bsum[i] : 0;
        s[tid] = v; __syncthreads();
        for (int d = 1; d < 256; d <<= 1) {
            int x = (tid >= d) ? s[tid - d] : 0;
            __syncthreads();
            s[tid] += x;
            __syncthreads();
        }
        if (i < NB) bsum[i] = carry + s[tid] - v;
        int tot = s[255];
        __syncthreads();
        carry += tot;
    }
}

__global__ void scan3(int* __restrict__ offs, const int* __restrict__ bsum) {
    int i = blockIdx.x * 256 + threadIdx.x;
    if (i < NR) offs[i] += bsum[i >> 8];
}

__global__ void edge_fill(const int* __restrict__ ei, const int* __restrict__ et,
                          const int* __restrict__ rank, const int* __restrict__ offs,
                          int* __restrict__ esrc_c, int* __restrict__ eseg_c) {
    int e = blockIdx.x * 256 + threadIdx.x;
    int s = ei[e], d = ei[EE + e], t = et[e];
    int seg = d * 8 + t;
    int slot = offs[seg] + rank[e];
    esrc_c[slot] = s;
    eseg_c[slot] = seg;
}

// weights -> bf16: WrB/WgB [r][kout][kd]; WaB [16][64] (rows 0-7 = Wa_src r, 8-15 = Wa_dst r)
__global__ void cvt_w(const float* __restrict__ Wr, const float* __restrict__ Wg,
                      const float* __restrict__ Wa,
                      unsigned short* __restrict__ WrB, unsigned short* __restrict__ WgB,
                      unsigned short* __restrict__ WaB) {
    int i = blockIdx.x * 256 + threadIdx.x;   // 32768 total
    WrB[i] = bf16r(Wr[i]);
    WgB[i] = bf16r(Wg[i]);
    if (i < 1024) {
        int row = i >> 6, k = i & 63;
        float v = (row < 8) ? Wa[row * 128 + k] : Wa[(row - 8) * 128 + 64 + k];
        WaB[i] = bf16r(v);
    }
}

// slot-parallel softmax: ex_c[slot] = exp(leaky(s_src+s_dst+b)); per-type denom
// (no max subtraction: |score|<~8, fp32-safe; softmax ratio shift-invariant)
__global__ void edge_softmax2(const int* __restrict__ esrc_c, const int* __restrict__ eseg_c,
                              const float* __restrict__ s_src, const float* __restrict__ s_dst,
                              const float* __restrict__ b_att,
                              float* __restrict__ ex_c, float* __restrict__ denomL) {
    __shared__ float lsum[4][8];
    int tid = threadIdx.x;
    if (tid < 32) lsum[tid >> 3][tid & 7] = 0.f;
    __syncthreads();
    int slot = blockIdx.x * 256 + tid;     // EE % 256 == 0
    int src = esrc_c[slot];
    int seg = eseg_c[slot];
    int t = seg & 7;
    float sc = s_src[src * 8 + t] + s_dst[seg] + b_att[t];
    sc = (sc >= 0.f) ? sc : NEG_SLOPE * sc;
    float ex = __expf(sc);
    ex_c[slot] = ex;
    atomicAdd(&lsum[tid >> 6][t], ex);
    __syncthreads();
    if (tid < 32) atomicAdd(&denomL[tid & 7], lsum[tid >> 3][tid & 7]);
}

// Fused combine, 16-node tiles (NN % 16 == 0 -> no node guards).
// Gather: owner-computes, no atomics: 16 threads/node, each owns an 8B bf16
// chunk; walks the node's 8 CSR segments accumulating in registers, plain
// LDS store per (node,r,chunk). One barrier, then 8 barrier-free MFMA phases.
// EMIT: also compute next-layer s_src/s_dst (MFMA vs WaB) + bf16 mirror.
template<bool EMIT>
__global__ __launch_bounds__(256, 4) void combine_fused(
    const float* __restrict__ hbuf, const unsigned short* __restrict__ hbf_in,
    const int* __restrict__ offs, const int* __restrict__ esrc_c,
    const float* __restrict__ ex_c, const float* __restrict__ denomL,
    const unsigned short* __restrict__ WrB, const unsigned short* __restrict__ WgB,
    const unsigned short* __restrict__ WaB, const float* __restrict__ b_gate,
    const float* __restrict__ gamma, const float* __restrict__ beta,
    float* __restrict__ hout, unsigned short* __restrict__ hbf_out,
    float* __restrict__ ssrc_out, float* __restrict__ sdst_out) {
    __shared__ float hs[16 * LDH];
    __shared__ float ps[PSW];
    __shared__ float idn8[8];
    __shared__ int offsL[129];
    int tid = threadIdx.x;
    int n0 = blockIdx.x * 16;

    // stage h tile (fp32), one float4 per thread
    {
        int row = tid >> 4, c4 = tid & 15;
        f4 v = ((const f4*)hbuf)[(size_t)(n0 + row) * 16 + c4];
        *(f4*)&hs[row * LDH + c4 * 4] = v;
    }
    if (tid < 129) {
        int sidx = n0 * 8 + tid;
        offsL[tid] = (sidx < NR) ? offs[sidx] : EE;
    }
    if (tid < 8) idn8[tid] = 1.f / denomL[tid];
    __syncthreads();

    int w = tid >> 6, lane = tid & 63;
    int quad = lane >> 4, lr = lane & 15;

    // A_h fragments
    bf8 a_h[2];
    #pragma unroll
    for (int kb = 0; kb < 2; ++kb) {
        const float* p = &hs[lr * LDH + kb * 32 + quad * 8];
        bf8 a;
        #pragma unroll
        for (int j = 0; j < 8; ++j) a[j] = (short)bf16r(p[j]);
        a_h[kb] = a;
    }

    // ---- gather: 16 threads per node, register accumulate, plain LDS store ----
    {
        int gn = tid >> 4, gc = tid & 15;      // node-in-tile, 4-float chunk
        int ob = gn * 8;
        #pragma unroll
        for (int r = 0; r < 8; ++r) {
            int lo = offsL[ob + r], hi = offsL[ob + r + 1];
            float sA = idn8[r];
            f4 fa = (f4){0.f, 0.f, 0.f, 0.f};
            for (int s = lo; s < hi; ++s) {
                float a = ex_c[s] * sA;
                int src = esrc_c[s];
                us4 hv = *(const us4*)(hbf_in + ((size_t)src << 6) + gc * 4);
                fa[0] += a * bf2f(hv[0]);
                fa[1] += a * bf2f(hv[1]);
                fa[2] += a * bf2f(hv[2]);
                fa[3] += a * bf2f(hv[3]);
            }
            *(f4*)&ps[gn * PND + r * 64 + gc * 4] = fa;
        }
    }
    __syncthreads();

    // ---- 8 relation MFMA phases (no barriers inside) ----
    f4 acc = (f4){0.f, 0.f, 0.f, 0.f};
    int tn = w;                       // this wave's 16 output cols
    for (int r = 0; r < 8; ++r) {
        bf8 a_p[2];
        #pragma unroll
        for (int kb = 0; kb < 2; ++kb) {
            const float* p = &ps[lr * PND + r * 64 + kb * 32 + quad * 8];
            bf8 a;
            #pragma unroll
            for (int j = 0; j < 8; ++j) a[j] = (short)bf16r(p[j]);
            a_p[kb] = a;
        }
        f4 aggc = (f4){0.f, 0.f, 0.f, 0.f};
        f4 gacc = (f4){0.f, 0.f, 0.f, 0.f};
        #pragma unroll
        for (int kb = 0; kb < 2; ++kb) {
            const bf8* br = (const bf8*)(WrB + ((r * 64 + tn * 16 + lr) * 64 + kb * 32 + quad * 8));
            const bf8* bg = (const bf8*)(WgB + ((r * 64 + tn * 16 + lr) * 64 + kb * 32 + quad * 8));
            aggc = __builtin_amdgcn_mfma_f32_16x16x32_bf16(a_p[kb], *br, aggc, 0, 0, 0);
            gacc = __builtin_amdgcn_mfma_f32_16x16x32_bf16(a_h[kb], *bg, gacc, 0, 0, 0);
        }
        float bg = b_gate[r * 64 + tn * 16 + lr];
        #pragma unroll
        for (int j = 0; j < 4; ++j) {
            float g = 1.f / (1.f + __expf(-(gacc[j] + bg)));
            acc[j] += g * aggc[j];
        }
    }
    __syncthreads();   // ps fully consumed before reuse

    // t = h + acc/8 into ps (stride LDH), C-layout positions
    #pragma unroll
    for (int j = 0; j < 4; ++j) {
        int row = quad * 4 + j;
        int col = tn * 16 + lr;
        ps[row * LDH + col] = hs[row * LDH + col] + acc[j] * 0.125f;
    }
    __syncthreads();

    // LN + ReLU; store hout; EMIT: o-tile + bf16 mirror
    {
        int row = tid >> 4, c = tid & 15;
        int n = n0 + row;
        f4 tv = *(const f4*)&ps[row * LDH + c * 4];
        float s1 = tv[0] + tv[1] + tv[2] + tv[3];
        float s2 = tv[0]*tv[0] + tv[1]*tv[1] + tv[2]*tv[2] + tv[3]*tv[3];
        #pragma unroll
        for (int off = 1; off <= 8; off <<= 1) {
            s1 += __shfl_xor(s1, off, 64);
            s2 += __shfl_xor(s2, off, 64);
        }
        float mu = s1 * (1.f / 64.f);
        float var = s2 * (1.f / 64.f) - mu * mu;
        float rs = rsqrtf(var + LN_EPS);
        f4 g = *(const f4*)(gamma + c * 4);
        f4 b = *(const f4*)(beta + c * 4);
        f4 ov;
        #pragma unroll
        for (int j = 0; j < 4; ++j)
            ov[j] = fmaxf((tv[j] - mu) * rs * g[j] + b[j], 0.f);
        *(f4*)(hout + (size_t)n * 64 + c * 4) = ov;
        if (EMIT) {
            *(f4*)&ps[OTB + row * LDH + c * 4] = ov;
            u2 u;
            u[0] = (unsigned)bf16r(ov[0]) | ((unsigned)bf16r(ov[1]) << 16);
            u[1] = (unsigned)bf16r(ov[2]) | ((unsigned)bf16r(ov[3]) << 16);
            *(u2*)(hbf_out + (size_t)n * 64 + c * 4) = u;
        }
    }

    if (EMIT) {
        __syncthreads();
        if (w == 0) {
            f4 sc = (f4){0.f, 0.f, 0.f, 0.f};
            #pragma unroll
            for (int kb = 0; kb < 2; ++kb) {
                const float* p = &ps[OTB + lr * LDH + kb * 32 + quad * 8];
                bf8 a;
                #pragma unroll
                for (int j = 0; j < 8; ++j) a[j] = (short)bf16r(p[j]);
                const bf8* bw = (const bf8*)(WaB + lr * 64 + kb * 32 + quad * 8);
                sc = __builtin_amdgcn_mfma_f32_16x16x32_bf16(a, *bw, sc, 0, 0, 0);
            }
            #pragma unroll
            for (int j = 0; j < 4; ++j) {
                int n = n0 + quad * 4 + j;
                if (lr < 8) ssrc_out[n * 8 + lr] = sc[j];
                else        sdst_out[n * 8 + (lr - 8)] = sc[j];
            }
        }
    }
}

extern "C" void kernel_launch(void* const* d_in, const int* in_sizes, int n_in,
                              void* d_out, int out_size, void* d_ws, size_t ws_size,
                              hipStream_t stream) {
    const float* x      = (const float*)d_in[0];
    const int*   ei     = (const int*)d_in[1];
    const int*   et     = (const int*)d_in[2];
    const float* W_in   = (const float*)d_in[3];
    const float* b_in   = (const float*)d_in[4];
    const float* W_rel  = (const float*)d_in[5];
    const float* W_gate = (const float*)d_in[6];
    const float* b_gate = (const float*)d_in[7];
    const float* W_att  = (const float*)d_in[8];
    const float* b_att  = (const float*)d_in[9];
    const float* ln_g   = (const float*)d_in[10];
    const float* ln_b   = (const float*)d_in[11];
    const float* W_out  = (const float*)d_in[12];
    const float* b_out  = (const float*)d_in[13];
    float* out = (float*)d_out;

    float* h0 = (float*)d_out;          // ping-pong A (scratch until final proj)

    char* ws = (char*)d_ws;
    float* h1 = (float*)ws;                     ws += (size_t)NN * 64 * 4;
    unsigned short* hbfA = (unsigned short*)ws; ws += (size_t)NN * 64 * 2;
    unsigned short* hbfB = (unsigned short*)ws; ws += (size_t)NN * 64 * 2;
    float* s_src = (float*)ws;                  ws += (size_t)NN * 8 * 4;
    float* s_dst = (float*)ws;                  ws += (size_t)NN * 8 * 4;
    unsigned short* WrB = (unsigned short*)ws;  ws += (size_t)RR * 64 * 64 * 2;
    unsigned short* WgB = (unsigned short*)ws;  ws += (size_t)RR * 64 * 64 * 2;
    unsigned short* WaB = (unsigned short*)ws;  ws += 2048;
    int* counts = (int*)ws;                     ws += (size_t)NR * 4;
    float* denoms = (float*)ws;                 ws += 128;       // 3x8 + pad
    int* offs = (int*)ws;                       ws += (size_t)NR * 4;
    int* bsum = (int*)ws;                       ws += 6400;
    int* rank = (int*)ws;                       ws += (size_t)EE * 4;
    int* esrc_c = (int*)ws;                     ws += (size_t)EE * 4;
    int* eseg_c = (int*)ws;                     ws += (size_t)EE * 4;
    float* ex_c = (float*)ws;                   ws += (size_t)EE * 4;

    hipMemsetAsync(counts, 0, (size_t)NR * 4 + 128, stream);    // counts + denoms
    cvt_w<<<128, 256, 0, stream>>>(W_rel, W_gate, W_att, WrB, WgB, WaB);
    edge_count<<<EE / 256, 256, 0, stream>>>(ei, et, counts, rank);
    scan1<<<NB, 256, 0, stream>>>(counts, offs, bsum);
    scan2<<<1, 256, 0, stream>>>(bsum);
    scan3<<<NB, 256, 0, stream>>>(offs, bsum);
    edge_fill<<<EE / 256, 256, 0, stream>>>(ei, et, rank, offs, esrc_c, eseg_c);
    proj64<true><<<(NN + 3) / 4, 256, 0, stream>>>(x, W_in, b_in, h0);
    att_pre<<<(NN + 31) / 32, 256, 0, stream>>>(h0, W_att, s_src, s_dst, hbfA);

    const int tiles16 = NN / 16;   // 3125, exact
    float* hA = h0;  float* hB = h1;
    unsigned short* bfA = hbfA;  unsigned short* bfB = hbfB;
    for (int layer = 0; layer < LL; ++layer) {
        edge_softmax2<<<EE / 256, 256, 0, stream>>>(esrc_c, eseg_c, s_src, s_dst,
                                                    b_att, ex_c, denoms + 8 * layer);
        if (layer < LL - 1) {
            combine_fused<true><<<tiles16, 256, 0, stream>>>(
                hA, bfA, offs, esrc_c, ex_c, denoms + 8 * layer,
                WrB, WgB, WaB, b_gate, ln_g + layer * 64, ln_b + layer * 64,
                hB, bfB, s_src, s_dst);
        } else {
            combine_fused<false><<<tiles16, 256, 0, stream>>>(
                hA, bfA, offs, esrc_c, ex_c, denoms + 8 * layer,
                WrB, WgB, WaB, b_gate, ln_g + layer * 64, ln_b + layer * 64,
                hB, bfB, s_src, s_dst);
        }
        float* tf = hA; hA = hB; hB = tf;
        unsigned short* tb = bfA; bfA = bfB; bfB = tb;
    }
    proj64<false><<<(NN + 3) / 4, 256, 0, stream>>>(hA, W_out, b_out, out);
}

// Round 7
// 609.381 us; speedup vs baseline: 2.7971x; 1.9444x over previous
//
#include <hip/hip_runtime.h>
#include <math.h>

#define NN 50000
#define EE 800000
#define HH 64
#define RR 8
#define LL 3
#define NR (NN * RR)            // 400000 segments
#define NB ((NR + 255) / 256)   // scan blocks
#define LN_EPS 1e-5f
#define NEG_SLOPE 0.2f
#define LDH 68                  // LDS row stride (floats) for 16x64 tiles
#define PND 516                 // ps node stride (words): 8*64+4 -> 2-way bank aliasing max
#define PSW (16 * PND)
#define OTB (16 * LDH)          // o-tile base inside ps (EMIT epilogue)
#define DSPREAD 64              // denom partial rows (distinct cachelines)

typedef __attribute__((ext_vector_type(8))) short bf8;
typedef __attribute__((ext_vector_type(4))) float f4;
typedef __attribute__((ext_vector_type(4))) unsigned short us4;
typedef __attribute__((ext_vector_type(2))) unsigned int u2;

__device__ __forceinline__ unsigned short bf16r(float f) {
    unsigned u = __float_as_uint(f);
    unsigned r = u + 0x7fffu + ((u >> 16) & 1u);
    return (unsigned short)(r >> 16);
}
__device__ __forceinline__ float bf2f(unsigned short u) {
    return __uint_as_float(((unsigned)u) << 16);
}

// out[n,k] = (relu?) dot(in[n,:], W[k,:]) + bias[k]   (64x64 weight)
template<bool RELU>
__global__ void proj64(const float* __restrict__ in, const float* __restrict__ W,
                       const float* __restrict__ bias, float* __restrict__ out) {
    __shared__ float WT[64 * 65];
    __shared__ float xs[4 * 64];
    int tid = threadIdx.x;
    #pragma unroll
    for (int s = 0; s < 16; ++s) {
        int idx = tid + 256 * s;
        int k = idx >> 6, i = idx & 63;
        WT[i * 65 + k] = W[idx];
    }
    int w = tid >> 6, l = tid & 63;
    int n = blockIdx.x * 4 + w;
    if (n < NN) xs[w * 64 + l] = in[n * 64 + l];
    __syncthreads();
    if (n >= NN) return;
    float acc = 0.f;
    #pragma unroll
    for (int i = 0; i < 64; ++i) acc += xs[w * 64 + i] * WT[i * 65 + l];
    acc += bias[l];
    if (RELU) acc = fmaxf(acc, 0.f);
    out[n * 64 + l] = acc;
}

// layer-0 only: s_src[n,r], s_dst[n,r] from h; emit bf16 mirror
__global__ void att_pre(const float* __restrict__ h, const float* __restrict__ W_att,
                        float* __restrict__ s_src, float* __restrict__ s_dst,
                        unsigned short* __restrict__ hbf) {
    __shared__ float hs[32 * 65];
    __shared__ float was[8 * 65];
    __shared__ float wad[8 * 65];
    int tid = threadIdx.x;
    int n0 = blockIdx.x * 32;
    #pragma unroll
    for (int s = 0; s < 4; ++s) {
        int idx = tid + 256 * s;
        int r = idx >> 7, c = idx & 127;
        float v = W_att[idx];
        if (c < 64) was[r * 65 + c] = v;
        else        wad[r * 65 + (c - 64)] = v;
    }
    #pragma unroll
    for (int s = 0; s < 8; ++s) {
        int idx = tid + 256 * s;
        int nl = idx >> 6, c = idx & 63;
        int n = n0 + nl;
        float v = 0.f;
        if (n < NN) {
            v = h[(size_t)n * 64 + c];
            hbf[(size_t)n * 64 + c] = bf16r(v);
        }
        hs[nl * 65 + c] = v;
    }
    __syncthreads();
    int nl = tid >> 3, r = tid & 7;
    int n = n0 + nl;
    if (n >= NN) return;
    float as = 0.f, ad = 0.f;
    #pragma unroll
    for (int k = 0; k < 64; ++k) {
        float hv = hs[nl * 65 + k];
        as += hv * was[r * 65 + k];
        ad += hv * wad[r * 65 + k];
    }
    s_src[n * 8 + r] = as;
    s_dst[n * 8 + r] = ad;
}

// ---- one-time CSR build (compact, exact) ----
__global__ void edge_count(const int* __restrict__ ei, const int* __restrict__ et,
                           int* __restrict__ counts, int* __restrict__ rank) {
    int e = blockIdx.x * 256 + threadIdx.x;
    int d = ei[EE + e], t = et[e];
    rank[e] = atomicAdd(&counts[d * 8 + t], 1);
}

__global__ void scan1(const int* __restrict__ counts, int* __restrict__ offs,
                      int* __restrict__ bsum) {
    __shared__ int s[256];
    int tid = threadIdx.x;
    int i = blockIdx.x * 256 + tid;
    int v = (i < NR) ? counts[i] : 0;
    s[tid] = v; __syncthreads();
    for (int d = 1; d < 256; d <<= 1) {
        int x = (tid >= d) ? s[tid - d] : 0;
        __syncthreads();
        s[tid] += x;
        __syncthreads();
    }
    if (i < NR) offs[i] = s[tid] - v;
    if (tid == 255) bsum[blockIdx.x] = s[255];
}

__global__ void scan2(int* __restrict__ bsum) {
    __shared__ int s[256];
    int tid = threadIdx.x;
    int carry = 0;
    for (int c0 = 0; c0 < NB; c0 += 256) {
        int i = c0 + tid;
        int v = (i < NB) ? bsum[i] : 0;
        s[tid] = v; __syncthreads();
        for (int d = 1; d < 256; d <<= 1) {
            int x = (tid >= d) ? s[tid - d] : 0;
            __syncthreads();
            s[tid] += x;
            __syncthreads();
        }
        if (i < NB) bsum[i] = carry + s[tid] - v;
        int tot = s[255];
        __syncthreads();
        carry += tot;
    }
}

__global__ void scan3(int* __restrict__ offs, const int* __restrict__ bsum) {
    int i = blockIdx.x * 256 + threadIdx.x;
    if (i < NR) offs[i] += bsum[i >> 8];
}

__global__ void edge_fill(const int* __restrict__ ei, const int* __restrict__ et,
                          const int* __restrict__ rank, const int* __restrict__ offs,
                          int* __restrict__ esrc_c, int* __restrict__ eseg_c) {
    int e = blockIdx.x * 256 + threadIdx.x;
    int s = ei[e], d = ei[EE + e], t = et[e];
    int seg = d * 8 + t;
    int slot = offs[seg] + rank[e];
    esrc_c[slot] = s;
    eseg_c[slot] = seg;
}

// weights -> bf16: WrB/WgB [r][kout][kd]; WaB [16][64] (rows 0-7 = Wa_src r, 8-15 = Wa_dst r)
__global__ void cvt_w(const float* __restrict__ Wr, const float* __restrict__ Wg,
                      const float* __restrict__ Wa,
                      unsigned short* __restrict__ WrB, unsigned short* __restrict__ WgB,
                      unsigned short* __restrict__ WaB) {
    int i = blockIdx.x * 256 + threadIdx.x;   // 32768 total
    WrB[i] = bf16r(Wr[i]);
    WgB[i] = bf16r(Wg[i]);
    if (i < 1024) {
        int row = i >> 6, k = i & 63;
        float v = (row < 8) ? Wa[row * 128 + k] : Wa[(row - 8) * 128 + 64 + k];
        WaB[i] = bf16r(v);
    }
}

// slot-parallel softmax; per-type denom via 64-way-spread partials
// (no max subtraction: |score|<~8, fp32-safe; softmax ratio shift-invariant)
__global__ void edge_softmax2(const int* __restrict__ esrc_c, const int* __restrict__ eseg_c,
                              const float* __restrict__ s_src, const float* __restrict__ s_dst,
                              const float* __restrict__ b_att,
                              float* __restrict__ ex_c, float* __restrict__ dpart) {
    __shared__ float lsum[4][8];
    int tid = threadIdx.x;
    if (tid < 32) lsum[tid >> 3][tid & 7] = 0.f;
    __syncthreads();
    int slot = blockIdx.x * 256 + tid;     // EE % 256 == 0
    int src = esrc_c[slot];
    int seg = eseg_c[slot];
    int t = seg & 7;
    float sc = s_src[src * 8 + t] + s_dst[seg] + b_att[t];
    sc = (sc >= 0.f) ? sc : NEG_SLOPE * sc;
    float ex = __expf(sc);
    ex_c[slot] = ex;
    atomicAdd(&lsum[tid >> 6][t], ex);
    __syncthreads();
    if (tid < 8) {
        float v = lsum[0][tid] + lsum[1][tid] + lsum[2][tid] + lsum[3][tid];
        // spread over 64 distinct cachelines (row stride 16 floats = 64 B)
        atomicAdd(&dpart[(blockIdx.x & (DSPREAD - 1)) * 16 + tid], v);
    }
}

// sum spread partials -> denomL; re-zero dpart for the next layer
__global__ void reduce_denom(float* __restrict__ dpart, float* __restrict__ denomL) {
    int tid = threadIdx.x;   // 64
    if (tid < 8) {
        float s = 0.f;
        #pragma unroll 8
        for (int j = 0; j < DSPREAD; ++j) s += dpart[j * 16 + tid];
        denomL[tid] = s;
    }
    __syncthreads();
    for (int i = tid; i < DSPREAD * 16; i += 64) dpart[i] = 0.f;
}

// Fused combine, 16-node tiles (NN % 16 == 0 -> no node guards).
// Gather: owner-computes, no atomics: 16 threads/node, each owns an 8B bf16
// chunk; walks the node's 8 CSR segments accumulating in registers, plain
// LDS store per (node,r,chunk). One barrier, then 8 barrier-free MFMA phases.
// EMIT: also compute next-layer s_src/s_dst (MFMA vs WaB) + bf16 mirror.
template<bool EMIT>
__global__ __launch_bounds__(256, 4) void combine_fused(
    const float* __restrict__ hbuf, const unsigned short* __restrict__ hbf_in,
    const int* __restrict__ offs, const int* __restrict__ esrc_c,
    const float* __restrict__ ex_c, const float* __restrict__ denomL,
    const unsigned short* __restrict__ WrB, const unsigned short* __restrict__ WgB,
    const unsigned short* __restrict__ WaB, const float* __restrict__ b_gate,
    const float* __restrict__ gamma, const float* __restrict__ beta,
    float* __restrict__ hout, unsigned short* __restrict__ hbf_out,
    float* __restrict__ ssrc_out, float* __restrict__ sdst_out) {
    __shared__ float hs[16 * LDH];
    __shared__ float ps[PSW];
    __shared__ float idn8[8];
    __shared__ int offsL[129];
    int tid = threadIdx.x;
    int n0 = blockIdx.x * 16;

    // stage h tile (fp32), one float4 per thread
    {
        int row = tid >> 4, c4 = tid & 15;
        f4 v = ((const f4*)hbuf)[(size_t)(n0 + row) * 16 + c4];
        *(f4*)&hs[row * LDH + c4 * 4] = v;
    }
    if (tid < 129) {
        int sidx = n0 * 8 + tid;
        offsL[tid] = (sidx < NR) ? offs[sidx] : EE;
    }
    if (tid < 8) idn8[tid] = 1.f / denomL[tid];
    __syncthreads();

    int w = tid >> 6, lane = tid & 63;
    int quad = lane >> 4, lr = lane & 15;

    // A_h fragments
    bf8 a_h[2];
    #pragma unroll
    for (int kb = 0; kb < 2; ++kb) {
        const float* p = &hs[lr * LDH + kb * 32 + quad * 8];
        bf8 a;
        #pragma unroll
        for (int j = 0; j < 8; ++j) a[j] = (short)bf16r(p[j]);
        a_h[kb] = a;
    }

    // ---- gather: 16 threads per node, register accumulate, plain LDS store ----
    {
        int gn = tid >> 4, gc = tid & 15;      // node-in-tile, 4-float chunk
        int ob = gn * 8;
        #pragma unroll
        for (int r = 0; r < 8; ++r) {
            int lo = offsL[ob + r], hi = offsL[ob + r + 1];
            float sA = idn8[r];
            f4 fa = (f4){0.f, 0.f, 0.f, 0.f};
            for (int s = lo; s < hi; ++s) {
                float a = ex_c[s] * sA;
                int src = esrc_c[s];
                us4 hv = *(const us4*)(hbf_in + ((size_t)src << 6) + gc * 4);
                fa[0] += a * bf2f(hv[0]);
                fa[1] += a * bf2f(hv[1]);
                fa[2] += a * bf2f(hv[2]);
                fa[3] += a * bf2f(hv[3]);
            }
            *(f4*)&ps[gn * PND + r * 64 + gc * 4] = fa;
        }
    }
    __syncthreads();

    // ---- 8 relation MFMA phases (no barriers inside) ----
    f4 acc = (f4){0.f, 0.f, 0.f, 0.f};
    int tn = w;                       // this wave's 16 output cols
    for (int r = 0; r < 8; ++r) {
        bf8 a_p[2];
        #pragma unroll
        for (int kb = 0; kb < 2; ++kb) {
            const float* p = &ps[lr * PND + r * 64 + kb * 32 + quad * 8];
            bf8 a;
            #pragma unroll
            for (int j = 0; j < 8; ++j) a[j] = (short)bf16r(p[j]);
            a_p[kb] = a;
        }
        f4 aggc = (f4){0.f, 0.f, 0.f, 0.f};
        f4 gacc = (f4){0.f, 0.f, 0.f, 0.f};
        #pragma unroll
        for (int kb = 0; kb < 2; ++kb) {
            const bf8* br = (const bf8*)(WrB + ((r * 64 + tn * 16 + lr) * 64 + kb * 32 + quad * 8));
            const bf8* bg = (const bf8*)(WgB + ((r * 64 + tn * 16 + lr) * 64 + kb * 32 + quad * 8));
            aggc = __builtin_amdgcn_mfma_f32_16x16x32_bf16(a_p[kb], *br, aggc, 0, 0, 0);
            gacc = __builtin_amdgcn_mfma_f32_16x16x32_bf16(a_h[kb], *bg, gacc, 0, 0, 0);
        }
        float bg = b_gate[r * 64 + tn * 16 + lr];
        #pragma unroll
        for (int j = 0; j < 4; ++j) {
            float g = 1.f / (1.f + __expf(-(gacc[j] + bg)));
            acc[j] += g * aggc[j];
        }
    }
    __syncthreads();   // ps fully consumed before reuse

    // t = h + acc/8 into ps (stride LDH), C-layout positions
    #pragma unroll
    for (int j = 0; j < 4; ++j) {
        int row = quad * 4 + j;
        int col = tn * 16 + lr;
        ps[row * LDH + col] = hs[row * LDH + col] + acc[j] * 0.125f;
    }
    __syncthreads();

    // LN + ReLU; store hout; EMIT: o-tile + bf16 mirror
    {
        int row = tid >> 4, c = tid & 15;
        int n = n0 + row;
        f4 tv = *(const f4*)&ps[row * LDH + c * 4];
        float s1 = tv[0] + tv[1] + tv[2] + tv[3];
        float s2 = tv[0]*tv[0] + tv[1]*tv[1] + tv[2]*tv[2] + tv[3]*tv[3];
        #pragma unroll
        for (int off = 1; off <= 8; off <<= 1) {
            s1 += __shfl_xor(s1, off, 64);
            s2 += __shfl_xor(s2, off, 64);
        }
        float mu = s1 * (1.f / 64.f);
        float var = s2 * (1.f / 64.f) - mu * mu;
        float rs = rsqrtf(var + LN_EPS);
        f4 g = *(const f4*)(gamma + c * 4);
        f4 b = *(const f4*)(beta + c * 4);
        f4 ov;
        #pragma unroll
        for (int j = 0; j < 4; ++j)
            ov[j] = fmaxf((tv[j] - mu) * rs * g[j] + b[j], 0.f);
        *(f4*)(hout + (size_t)n * 64 + c * 4) = ov;
        if (EMIT) {
            *(f4*)&ps[OTB + row * LDH + c * 4] = ov;
            u2 u;
            u[0] = (unsigned)bf16r(ov[0]) | ((unsigned)bf16r(ov[1]) << 16);
            u[1] = (unsigned)bf16r(ov[2]) | ((unsigned)bf16r(ov[3]) << 16);
            *(u2*)(hbf_out + (size_t)n * 64 + c * 4) = u;
        }
    }

    if (EMIT) {
        __syncthreads();
        if (w == 0) {
            f4 sc = (f4){0.f, 0.f, 0.f, 0.f};
            #pragma unroll
            for (int kb = 0; kb < 2; ++kb) {
                const float* p = &ps[OTB + lr * LDH + kb * 32 + quad * 8];
                bf8 a;
                #pragma unroll
                for (int j = 0; j < 8; ++j) a[j] = (short)bf16r(p[j]);
                const bf8* bw = (const bf8*)(WaB + lr * 64 + kb * 32 + quad * 8);
                sc = __builtin_amdgcn_mfma_f32_16x16x32_bf16(a, *bw, sc, 0, 0, 0);
            }
            #pragma unroll
            for (int j = 0; j < 4; ++j) {
                int n = n0 + quad * 4 + j;
                if (lr < 8) ssrc_out[n * 8 + lr] = sc[j];
                else        sdst_out[n * 8 + (lr - 8)] = sc[j];
            }
        }
    }
}

extern "C" void kernel_launch(void* const* d_in, const int* in_sizes, int n_in,
                              void* d_out, int out_size, void* d_ws, size_t ws_size,
                              hipStream_t stream) {
    const float* x      = (const float*)d_in[0];
    const int*   ei     = (const int*)d_in[1];
    const int*   et     = (const int*)d_in[2];
    const float* W_in   = (const float*)d_in[3];
    const float* b_in   = (const float*)d_in[4];
    const float* W_rel  = (const float*)d_in[5];
    const float* W_gate = (const float*)d_in[6];
    const float* b_gate = (const float*)d_in[7];
    const float* W_att  = (const float*)d_in[8];
    const float* b_att  = (const float*)d_in[9];
    const float* ln_g   = (const float*)d_in[10];
    const float* ln_b   = (const float*)d_in[11];
    const float* W_out  = (const float*)d_in[12];
    const float* b_out  = (const float*)d_in[13];
    float* out = (float*)d_out;

    float* h0 = (float*)d_out;          // ping-pong A (scratch until final proj)

    char* ws = (char*)d_ws;
    float* h1 = (float*)ws;                     ws += (size_t)NN * 64 * 4;
    unsigned short* hbfA = (unsigned short*)ws; ws += (size_t)NN * 64 * 2;
    unsigned short* hbfB = (unsigned short*)ws; ws += (size_t)NN * 64 * 2;
    float* s_src = (float*)ws;                  ws += (size_t)NN * 8 * 4;
    float* s_dst = (float*)ws;                  ws += (size_t)NN * 8 * 4;
    unsigned short* WrB = (unsigned short*)ws;  ws += (size_t)RR * 64 * 64 * 2;
    unsigned short* WgB = (unsigned short*)ws;  ws += (size_t)RR * 64 * 64 * 2;
    unsigned short* WaB = (unsigned short*)ws;  ws += 2048;
    // contiguous zero region: counts + denoms + dpart
    int* counts = (int*)ws;                     ws += (size_t)NR * 4;
    float* denoms = (float*)ws;                 ws += 128;       // 3x8 + pad
    float* dpart = (float*)ws;                  ws += DSPREAD * 16 * 4;
    int* offs = (int*)ws;                       ws += (size_t)NR * 4;
    int* bsum = (int*)ws;                       ws += 6400;
    int* rank = (int*)ws;                       ws += (size_t)EE * 4;
    int* esrc_c = (int*)ws;                     ws += (size_t)EE * 4;
    int* eseg_c = (int*)ws;                     ws += (size_t)EE * 4;
    float* ex_c = (float*)ws;                   ws += (size_t)EE * 4;

    hipMemsetAsync(counts, 0, (size_t)NR * 4 + 128 + DSPREAD * 16 * 4, stream);
    cvt_w<<<128, 256, 0, stream>>>(W_rel, W_gate, W_att, WrB, WgB, WaB);
    edge_count<<<EE / 256, 256, 0, stream>>>(ei, et, counts, rank);
    scan1<<<NB, 256, 0, stream>>>(counts, offs, bsum);
    scan2<<<1, 256, 0, stream>>>(bsum);
    scan3<<<NB, 256, 0, stream>>>(offs, bsum);
    edge_fill<<<EE / 256, 256, 0, stream>>>(ei, et, rank, offs, esrc_c, eseg_c);
    proj64<true><<<(NN + 3) / 4, 256, 0, stream>>>(x, W_in, b_in, h0);
    att_pre<<<(NN + 31) / 32, 256, 0, stream>>>(h0, W_att, s_src, s_dst, hbfA);

    const int tiles16 = NN / 16;   // 3125, exact
    float* hA = h0;  float* hB = h1;
    unsigned short* bfA = hbfA;  unsigned short* bfB = hbfB;
    for (int layer = 0; layer < LL; ++layer) {
        edge_softmax2<<<EE / 256, 256, 0, stream>>>(esrc_c, eseg_c, s_src, s_dst,
                                                    b_att, ex_c, dpart);
        reduce_denom<<<1, 64, 0, stream>>>(dpart, denoms + 8 * layer);
        if (layer < LL - 1) {
            combine_fused<true><<<tiles16, 256, 0, stream>>>(
                hA, bfA, offs, esrc_c, ex_c, denoms + 8 * layer,
                WrB, WgB, WaB, b_gate, ln_g + layer * 64, ln_b + layer * 64,
                hB, bfB, s_src, s_dst);
        } else {
            combine_fused<false><<<tiles16, 256, 0, stream>>>(
                hA, bfA, offs, esrc_c, ex_c, denoms + 8 * layer,
                WrB, WgB, WaB, b_gate, ln_g + layer * 64, ln_b + layer * 64,
                hB, bfB, s_src, s_dst);
        }
        float* tf = hA; hA = hB; hB = tf;
        unsigned short* tb = bfA; bfA = bfB; bfB = tb;
    }
    proj64<false><<<(NN + 3) / 4, 256, 0, stream>>>(hA, W_out, b_out, out);
}

// Round 8
// 460.516 us; speedup vs baseline: 3.7013x; 1.3233x over previous
//
#include <hip/hip_runtime.h>
#include <math.h>

#define NN 50000
#define EE 800000
#define HH 64
#define RR 8
#define LL 3
#define NR (NN * RR)            // 400000 segments
#define NB ((NR + 255) / 256)   // scan blocks
#define LN_EPS 1e-5f
#define NEG_SLOPE 0.2f
#define LDH 68                  // LDS row stride (floats) for 16x64 fp32 tiles
#define PNB 584                 // ps node stride (bf16 units): 8*72 + 8 pad
#define OTB (16 * LDH)          // o-tile base inside ps_f (EMIT epilogue)
#define DSPREAD 64              // denom partial rows (distinct cachelines)

typedef __attribute__((ext_vector_type(8))) short bf8;
typedef __attribute__((ext_vector_type(4))) float f4;
typedef __attribute__((ext_vector_type(8))) unsigned short us8;
typedef __attribute__((ext_vector_type(2))) unsigned int u2;

__device__ __forceinline__ unsigned short bf16r(float f) {
    unsigned u = __float_as_uint(f);
    unsigned r = u + 0x7fffu + ((u >> 16) & 1u);
    return (unsigned short)(r >> 16);
}
__device__ __forceinline__ float bf2f(unsigned short u) {
    return __uint_as_float(((unsigned)u) << 16);
}

// out[n,k] = (relu?) dot(in[n,:], W[k,:]) + bias[k]   (64x64 weight)
template<bool RELU>
__global__ void proj64(const float* __restrict__ in, const float* __restrict__ W,
                       const float* __restrict__ bias, float* __restrict__ out) {
    __shared__ float WT[64 * 65];
    __shared__ float xs[4 * 64];
    int tid = threadIdx.x;
    #pragma unroll
    for (int s = 0; s < 16; ++s) {
        int idx = tid + 256 * s;
        int k = idx >> 6, i = idx & 63;
        WT[i * 65 + k] = W[idx];
    }
    int w = tid >> 6, l = tid & 63;
    int n = blockIdx.x * 4 + w;
    if (n < NN) xs[w * 64 + l] = in[n * 64 + l];
    __syncthreads();
    if (n >= NN) return;
    float acc = 0.f;
    #pragma unroll
    for (int i = 0; i < 64; ++i) acc += xs[w * 64 + i] * WT[i * 65 + l];
    acc += bias[l];
    if (RELU) acc = fmaxf(acc, 0.f);
    out[n * 64 + l] = acc;
}

// layer-0 only: s_src[n,r], s_dst[n,r] from h; emit bf16 mirror
__global__ void att_pre(const float* __restrict__ h, const float* __restrict__ W_att,
                        float* __restrict__ s_src, float* __restrict__ s_dst,
                        unsigned short* __restrict__ hbf) {
    __shared__ float hs[32 * 65];
    __shared__ float was[8 * 65];
    __shared__ float wad[8 * 65];
    int tid = threadIdx.x;
    int n0 = blockIdx.x * 32;
    #pragma unroll
    for (int s = 0; s < 4; ++s) {
        int idx = tid + 256 * s;
        int r = idx >> 7, c = idx & 127;
        float v = W_att[idx];
        if (c < 64) was[r * 65 + c] = v;
        else        wad[r * 65 + (c - 64)] = v;
    }
    #pragma unroll
    for (int s = 0; s < 8; ++s) {
        int idx = tid + 256 * s;
        int nl = idx >> 6, c = idx & 63;
        int n = n0 + nl;
        float v = 0.f;
        if (n < NN) {
            v = h[(size_t)n * 64 + c];
            hbf[(size_t)n * 64 + c] = bf16r(v);
        }
        hs[nl * 65 + c] = v;
    }
    __syncthreads();
    int nl = tid >> 3, r = tid & 7;
    int n = n0 + nl;
    if (n >= NN) return;
    float as = 0.f, ad = 0.f;
    #pragma unroll
    for (int k = 0; k < 64; ++k) {
        float hv = hs[nl * 65 + k];
        as += hv * was[r * 65 + k];
        ad += hv * wad[r * 65 + k];
    }
    s_src[n * 8 + r] = as;
    s_dst[n * 8 + r] = ad;
}

// ---- one-time CSR build (compact, exact) ----
__global__ void edge_count(const int* __restrict__ ei, const int* __restrict__ et,
                           int* __restrict__ counts, int* __restrict__ rank) {
    int e = blockIdx.x * 256 + threadIdx.x;
    int d = ei[EE + e], t = et[e];
    rank[e] = atomicAdd(&counts[d * 8 + t], 1);
}

__global__ void scan1(const int* __restrict__ counts, int* __restrict__ offs,
                      int* __restrict__ bsum) {
    __shared__ int s[256];
    int tid = threadIdx.x;
    int i = blockIdx.x * 256 + tid;
    int v = (i < NR) ? counts[i] : 0;
    s[tid] = v; __syncthreads();
    for (int d = 1; d < 256; d <<= 1) {
        int x = (tid >= d) ? s[tid - d] : 0;
        __syncthreads();
        s[tid] += x;
        __syncthreads();
    }
    if (i < NR) offs[i] = s[tid] - v;
    if (tid == 255) bsum[blockIdx.x] = s[255];
}

__global__ void scan2(int* __restrict__ bsum) {
    __shared__ int s[256];
    int tid = threadIdx.x;
    int carry = 0;
    for (int c0 = 0; c0 < NB; c0 += 256) {
        int i = c0 + tid;
        int v = (i < NB) ? bsum[i] : 0;
        s[tid] = v; __syncthreads();
        for (int d = 1; d < 256; d <<= 1) {
            int x = (tid >= d) ? s[tid - d] : 0;
            __syncthreads();
            s[tid] += x;
            __syncthreads();
        }
        if (i < NB) bsum[i] = carry + s[tid] - v;
        int tot = s[255];
        __syncthreads();
        carry += tot;
    }
}

__global__ void scan3(int* __restrict__ offs, const int* __restrict__ bsum) {
    int i = blockIdx.x * 256 + threadIdx.x;
    if (i < NR) offs[i] += bsum[i >> 8];
}

// spack[slot] = {src, seg}
__global__ void edge_fill(const int* __restrict__ ei, const int* __restrict__ et,
                          const int* __restrict__ rank, const int* __restrict__ offs,
                          u2* __restrict__ spack) {
    int e = blockIdx.x * 256 + threadIdx.x;
    int s = ei[e], d = ei[EE + e], t = et[e];
    int seg = d * 8 + t;
    int slot = offs[seg] + rank[e];
    spack[slot] = (u2){(unsigned)s, (unsigned)seg};
}

// weights -> bf16: WrB/WgB [r][kout][kd]; WaB [16][64] (rows 0-7 = Wa_src r, 8-15 = Wa_dst r)
__global__ void cvt_w(const float* __restrict__ Wr, const float* __restrict__ Wg,
                      const float* __restrict__ Wa,
                      unsigned short* __restrict__ WrB, unsigned short* __restrict__ WgB,
                      unsigned short* __restrict__ WaB) {
    int i = blockIdx.x * 256 + threadIdx.x;   // 32768 total
    WrB[i] = bf16r(Wr[i]);
    WgB[i] = bf16r(Wg[i]);
    if (i < 1024) {
        int row = i >> 6, k = i & 63;
        float v = (row < 8) ? Wa[row * 128 + k] : Wa[(row - 8) * 128 + 64 + k];
        WaB[i] = bf16r(v);
    }
}

// slot-parallel softmax; epack[slot] = {src, ex}; per-type denom via spread partials
// (no max subtraction: |score|<~8, fp32-safe; softmax ratio shift-invariant)
__global__ void edge_softmax2(const u2* __restrict__ spack,
                              const float* __restrict__ s_src, const float* __restrict__ s_dst,
                              const float* __restrict__ b_att,
                              u2* __restrict__ epack, float* __restrict__ dpart) {
    __shared__ float lsum[4][8];
    int tid = threadIdx.x;
    if (tid < 32) lsum[tid >> 3][tid & 7] = 0.f;
    __syncthreads();
    int slot = blockIdx.x * 256 + tid;     // EE % 256 == 0
    u2 sp = spack[slot];
    int src = (int)sp[0];
    int seg = (int)sp[1];
    int t = seg & 7;
    float sc = s_src[src * 8 + t] + s_dst[seg] + b_att[t];
    sc = (sc >= 0.f) ? sc : NEG_SLOPE * sc;
    float ex = __expf(sc);
    epack[slot] = (u2){(unsigned)src, __float_as_uint(ex)};
    atomicAdd(&lsum[tid >> 6][t], ex);
    __syncthreads();
    if (tid < 8) {
        float v = lsum[0][tid] + lsum[1][tid] + lsum[2][tid] + lsum[3][tid];
        atomicAdd(&dpart[(blockIdx.x & (DSPREAD - 1)) * 16 + tid], v);
    }
}

// sum spread partials -> denomL; re-zero dpart for the next layer
__global__ void reduce_denom(float* __restrict__ dpart, float* __restrict__ denomL) {
    int tid = threadIdx.x;   // 64
    if (tid < 8) {
        float s = 0.f;
        #pragma unroll 8
        for (int j = 0; j < DSPREAD; ++j) s += dpart[j * 16 + tid];
        denomL[tid] = s;
    }
    __syncthreads();
    for (int i = tid; i < DSPREAD * 16; i += 64) dpart[i] = 0.f;
}

// Fused combine, 16-node tiles (NN % 16 == 0).
// Gather: one (node,r) segment per thread-PAIR (128 segs x 2 halves = 256 thr);
// each thread owns 32 cols, walks its segment (avg 2 edges), accumulates fp32
// in regs, scales once by 1/denom, stores bf16 to ps. MFMA A_p reads are then
// direct ds_read_b128 (no converts). One barrier between gather and MFMA.
// EMIT: also compute next-layer s_src/s_dst (MFMA vs WaB) + bf16 mirror.
template<bool EMIT>
__global__ __launch_bounds__(256, 5) void combine_fused(
    const float* __restrict__ hbuf, const unsigned short* __restrict__ hbf_in,
    const int* __restrict__ offs, const u2* __restrict__ epack,
    const float* __restrict__ denomL,
    const unsigned short* __restrict__ WrB, const unsigned short* __restrict__ WgB,
    const unsigned short* __restrict__ WaB, const float* __restrict__ b_gate,
    const float* __restrict__ gamma, const float* __restrict__ beta,
    float* __restrict__ hout, unsigned short* __restrict__ hbf_out,
    float* __restrict__ ssrc_out, float* __restrict__ sdst_out) {
    __shared__ float hs[16 * LDH];
    __shared__ alignas(16) unsigned short ps[16 * PNB];   // bf16 pre-tile, 18688 B
    __shared__ float idn8[8];
    __shared__ int offsL[129];
    float* ps_f = (float*)ps;                             // reused fp32 in epilogue
    int tid = threadIdx.x;
    int n0 = blockIdx.x * 16;

    // stage h tile (fp32), one float4 per thread
    {
        int row = tid >> 4, c4 = tid & 15;
        f4 v = ((const f4*)hbuf)[(size_t)(n0 + row) * 16 + c4];
        *(f4*)&hs[row * LDH + c4 * 4] = v;
    }
    if (tid < 129) {
        int sidx = n0 * 8 + tid;
        offsL[tid] = (sidx < NR) ? offs[sidx] : EE;
    }
    if (tid < 8) idn8[tid] = 1.f / denomL[tid];
    __syncthreads();

    // ---- gather: segment-parallel, register accumulate, bf16 LDS store ----
    {
        int segl = tid >> 1;            // local (node,r): 0..127
        int half = tid & 1;             // 32-col half
        int lo = offsL[segl], hi = offsL[segl + 1];
        int r = segl & 7;
        int gn = segl >> 3;
        float fa[32];
        #pragma unroll
        for (int j = 0; j < 32; ++j) fa[j] = 0.f;
        for (int s = lo; s < hi; ++s) {
            u2 pk = epack[s];
            int src = (int)pk[0];
            float a = __uint_as_float(pk[1]);
            const us8* hp = (const us8*)(hbf_in + ((size_t)src << 6) + half * 32);
            #pragma unroll
            for (int q = 0; q < 4; ++q) {
                us8 hv = hp[q];
                #pragma unroll
                for (int j = 0; j < 8; ++j)
                    fa[q * 8 + j] += a * bf2f(hv[j]);
            }
        }
        float sA = idn8[r];
        unsigned short* pp = &ps[gn * PNB + r * 72 + half * 32];
        #pragma unroll
        for (int q = 0; q < 4; ++q) {
            us8 o;
            #pragma unroll
            for (int j = 0; j < 8; ++j) o[j] = bf16r(fa[q * 8 + j] * sA);
            *(us8*)(pp + q * 8) = o;
        }
    }
    __syncthreads();

    int w = tid >> 6, lane = tid & 63;
    int quad = lane >> 4, lr = lane & 15;
    int tn = w;                       // this wave's 16 output cols

    // A_h fragments (built after gather to lower live-register pressure)
    bf8 a_h[2];
    #pragma unroll
    for (int kb = 0; kb < 2; ++kb) {
        const float* p = &hs[lr * LDH + kb * 32 + quad * 8];
        bf8 a;
        #pragma unroll
        for (int j = 0; j < 8; ++j) a[j] = (short)bf16r(p[j]);
        a_h[kb] = a;
    }

    // ---- 8 relation MFMA phases (no barriers inside) ----
    f4 acc = (f4){0.f, 0.f, 0.f, 0.f};
    for (int r = 0; r < 8; ++r) {
        bf8 a_p[2];
        #pragma unroll
        for (int kb = 0; kb < 2; ++kb)
            a_p[kb] = *(const bf8*)&ps[lr * PNB + r * 72 + kb * 32 + quad * 8];
        f4 aggc = (f4){0.f, 0.f, 0.f, 0.f};
        f4 gacc = (f4){0.f, 0.f, 0.f, 0.f};
        #pragma unroll
        for (int kb = 0; kb < 2; ++kb) {
            const bf8* br = (const bf8*)(WrB + ((r * 64 + tn * 16 + lr) * 64 + kb * 32 + quad * 8));
            const bf8* bg = (const bf8*)(WgB + ((r * 64 + tn * 16 + lr) * 64 + kb * 32 + quad * 8));
            aggc = __builtin_amdgcn_mfma_f32_16x16x32_bf16(a_p[kb], *br, aggc, 0, 0, 0);
            gacc = __builtin_amdgcn_mfma_f32_16x16x32_bf16(a_h[kb], *bg, gacc, 0, 0, 0);
        }
        float bg = b_gate[r * 64 + tn * 16 + lr];
        #pragma unroll
        for (int j = 0; j < 4; ++j) {
            float g = 1.f / (1.f + __expf(-(gacc[j] + bg)));
            acc[j] += g * aggc[j];
        }
    }
    __syncthreads();   // ps fully consumed before fp32 reuse

    // t = h + acc/8 into ps_f (stride LDH), C-layout positions
    #pragma unroll
    for (int j = 0; j < 4; ++j) {
        int row = quad * 4 + j;
        int col = tn * 16 + lr;
        ps_f[row * LDH + col] = hs[row * LDH + col] + acc[j] * 0.125f;
    }
    __syncthreads();

    // LN + ReLU; store hout; EMIT: o-tile + bf16 mirror
    {
        int row = tid >> 4, c = tid & 15;
        int n = n0 + row;
        f4 tv = *(const f4*)&ps_f[row * LDH + c * 4];
        float s1 = tv[0] + tv[1] + tv[2] + tv[3];
        float s2 = tv[0]*tv[0] + tv[1]*tv[1] + tv[2]*tv[2] + tv[3]*tv[3];
        #pragma unroll
        for (int off = 1; off <= 8; off <<= 1) {
            s1 += __shfl_xor(s1, off, 64);
            s2 += __shfl_xor(s2, off, 64);
        }
        float mu = s1 * (1.f / 64.f);
        float var = s2 * (1.f / 64.f) - mu * mu;
        float rs = rsqrtf(var + LN_EPS);
        f4 g = *(const f4*)(gamma + c * 4);
        f4 b = *(const f4*)(beta + c * 4);
        f4 ov;
        #pragma unroll
        for (int j = 0; j < 4; ++j)
            ov[j] = fmaxf((tv[j] - mu) * rs * g[j] + b[j], 0.f);
        *(f4*)(hout + (size_t)n * 64 + c * 4) = ov;
        if (EMIT) {
            *(f4*)&ps_f[OTB + row * LDH + c * 4] = ov;
            u2 u;
            u[0] = (unsigned)bf16r(ov[0]) | ((unsigned)bf16r(ov[1]) << 16);
            u[1] = (unsigned)bf16r(ov[2]) | ((unsigned)bf16r(ov[3]) << 16);
            *(u2*)(hbf_out + (size_t)n * 64 + c * 4) = u;
        }
    }

    if (EMIT) {
        __syncthreads();
        if (w == 0) {
            f4 sc = (f4){0.f, 0.f, 0.f, 0.f};
            #pragma unroll
            for (int kb = 0; kb < 2; ++kb) {
                const float* p = &ps_f[OTB + lr * LDH + kb * 32 + quad * 8];
                bf8 a;
                #pragma unroll
                for (int j = 0; j < 8; ++j) a[j] = (short)bf16r(p[j]);
                const bf8* bw = (const bf8*)(WaB + lr * 64 + kb * 32 + quad * 8);
                sc = __builtin_amdgcn_mfma_f32_16x16x32_bf16(a, *bw, sc, 0, 0, 0);
            }
            #pragma unroll
            for (int j = 0; j < 4; ++j) {
                int n = n0 + quad * 4 + j;
                if (lr < 8) ssrc_out[n * 8 + lr] = sc[j];
                else        sdst_out[n * 8 + (lr - 8)] = sc[j];
            }
        }
    }
}

extern "C" void kernel_launch(void* const* d_in, const int* in_sizes, int n_in,
                              void* d_out, int out_size, void* d_ws, size_t ws_size,
                              hipStream_t stream) {
    const float* x      = (const float*)d_in[0];
    const int*   ei     = (const int*)d_in[1];
    const int*   et     = (const int*)d_in[2];
    const float* W_in   = (const float*)d_in[3];
    const float* b_in   = (const float*)d_in[4];
    const float* W_rel  = (const float*)d_in[5];
    const float* W_gate = (const float*)d_in[6];
    const float* b_gate = (const float*)d_in[7];
    const float* W_att  = (const float*)d_in[8];
    const float* b_att  = (const float*)d_in[9];
    const float* ln_g   = (const float*)d_in[10];
    const float* ln_b   = (const float*)d_in[11];
    const float* W_out  = (const float*)d_in[12];
    const float* b_out  = (const float*)d_in[13];
    float* out = (float*)d_out;

    float* h0 = (float*)d_out;          // ping-pong A (scratch until final proj)

    char* ws = (char*)d_ws;
    float* h1 = (float*)ws;                     ws += (size_t)NN * 64 * 4;
    unsigned short* hbfA = (unsigned short*)ws; ws += (size_t)NN * 64 * 2;
    unsigned short* hbfB = (unsigned short*)ws; ws += (size_t)NN * 64 * 2;
    float* s_src = (float*)ws;                  ws += (size_t)NN * 8 * 4;
    float* s_dst = (float*)ws;                  ws += (size_t)NN * 8 * 4;
    unsigned short* WrB = (unsigned short*)ws;  ws += (size_t)RR * 64 * 64 * 2;
    unsigned short* WgB = (unsigned short*)ws;  ws += (size_t)RR * 64 * 64 * 2;
    unsigned short* WaB = (unsigned short*)ws;  ws += 2048;
    // contiguous zero region: counts + denoms + dpart
    int* counts = (int*)ws;                     ws += (size_t)NR * 4;
    float* denoms = (float*)ws;                 ws += 128;       // 3x8 + pad
    float* dpart = (float*)ws;                  ws += DSPREAD * 16 * 4;
    int* offs = (int*)ws;                       ws += (size_t)NR * 4;
    int* bsum = (int*)ws;                       ws += 6400;
    int* rank = (int*)ws;                       ws += (size_t)EE * 4;
    u2* spack = (u2*)ws;                        ws += (size_t)EE * 8;
    u2* epack = (u2*)ws;                        ws += (size_t)EE * 8;

    hipMemsetAsync(counts, 0, (size_t)NR * 4 + 128 + DSPREAD * 16 * 4, stream);
    cvt_w<<<128, 256, 0, stream>>>(W_rel, W_gate, W_att, WrB, WgB, WaB);
    edge_count<<<EE / 256, 256, 0, stream>>>(ei, et, counts, rank);
    scan1<<<NB, 256, 0, stream>>>(counts, offs, bsum);
    scan2<<<1, 256, 0, stream>>>(bsum);
    scan3<<<NB, 256, 0, stream>>>(offs, bsum);
    edge_fill<<<EE / 256, 256, 0, stream>>>(ei, et, rank, offs, spack);
    proj64<true><<<(NN + 3) / 4, 256, 0, stream>>>(x, W_in, b_in, h0);
    att_pre<<<(NN + 31) / 32, 256, 0, stream>>>(h0, W_att, s_src, s_dst, hbfA);

    const int tiles16 = NN / 16;   // 3125, exact
    float* hA = h0;  float* hB = h1;
    unsigned short* bfA = hbfA;  unsigned short* bfB = hbfB;
    for (int layer = 0; layer < LL; ++layer) {
        edge_softmax2<<<EE / 256, 256, 0, stream>>>(spack, s_src, s_dst, b_att,
                                                    epack, dpart);
        reduce_denom<<<1, 64, 0, stream>>>(dpart, denoms + 8 * layer);
        if (layer < LL - 1) {
            combine_fused<true><<<tiles16, 256, 0, stream>>>(
                hA, bfA, offs, epack, denoms + 8 * layer,
                WrB, WgB, WaB, b_gate, ln_g + layer * 64, ln_b + layer * 64,
                hB, bfB, s_src, s_dst);
        } else {
            combine_fused<false><<<tiles16, 256, 0, stream>>>(
                hA, bfA, offs, epack, denoms + 8 * layer,
                WrB, WgB, WaB, b_gate, ln_g + layer * 64, ln_b + layer * 64,
                hB, bfB, s_src, s_dst);
        }
        float* tf = hA; hA = hB; hB = tf;
        unsigned short* tb = bfA; bfA = bfB; bfB = tb;
    }
    proj64<false><<<(NN + 3) / 4, 256, 0, stream>>>(hA, W_out, b_out, out);
}